// Round 3
// baseline (304.356 us; speedup 1.0000x reference)
//
#include <hip/hip_runtime.h>

#define Bb 32
#define Ss 2048
#define Hh 1024

typedef __attribute__((ext_vector_type(4))) float f32x4;
typedef __attribute__((ext_vector_type(8))) short s16x8;

#define GAS const __attribute__((address_space(1))) unsigned int
#define LAS __attribute__((address_space(3))) unsigned int

__device__ __forceinline__ unsigned short f2bf(float x) {
  unsigned int u = __float_as_uint(x);
  u = (u + 0x7fffu + ((u >> 16) & 1u)) >> 16;
  return (unsigned short)u;
}

// fp32 [rows][1024] -> bf16, tiled ((row>>8)*32 + (k>>5)) 16KB blocks, PRE-SWIZZLED:
// within tile: byte = r*64 + ((2*(k&31)) ^ ((r&3)<<4)), r = row&255.
// GEMM stages these linearly via global_load_lds; ds_read applies the same XOR.
__global__ void cvt_swz_kernel(const float* __restrict__ in, unsigned short* __restrict__ out) {
  int g = blockIdx.x * blockDim.x + threadIdx.x;
  int row = g >> 7;
  int kc8 = (g & 127) << 3;
  const float4* src = reinterpret_cast<const float4*>(in + (size_t)row * Hh + kc8);
  float4 a = src[0], b = src[1];
  union { unsigned short u[8]; uint4 q; } rr;
  rr.u[0] = f2bf(a.x); rr.u[1] = f2bf(a.y); rr.u[2] = f2bf(a.z); rr.u[3] = f2bf(a.w);
  rr.u[4] = f2bf(b.x); rr.u[5] = f2bf(b.y); rr.u[6] = f2bf(b.z); rr.u[7] = f2bf(b.w);
  int r = row & 255;
  size_t byte = ((size_t)(row >> 8) * 32 + (kc8 >> 5)) * 16384
              + (size_t)(r * 64 + (((kc8 & 31) * 2) ^ ((r & 3) << 4)));
  *reinterpret_cast<uint4*>(reinterpret_cast<char*>(out) + byte) = rr.q;
}

// ---- dec_feature[b][o] = dot(dh[b], W_dec[o]) + b_dec[o], fp32, wave per (b,o) ----
__global__ void dec_feat_kernel(const float* __restrict__ dh,
                                const float* __restrict__ Wd,
                                const float* __restrict__ bd,
                                float* __restrict__ out) {
  int gw = blockIdx.x * 4 + (threadIdx.x >> 6);
  int lane = threadIdx.x & 63;
  int b = gw >> 10;
  int o = gw & 1023;
  const float4* x = reinterpret_cast<const float4*>(dh + (size_t)b * Hh);
  const float4* w = reinterpret_cast<const float4*>(Wd + (size_t)o * Hh);
  float acc = 0.f;
#pragma unroll
  for (int it = 0; it < 4; ++it) {
    float4 xa = x[lane + it * 64];
    float4 wa = w[lane + it * 64];
    acc += xa.x * wa.x + xa.y * wa.y + xa.z * wa.z + xa.w * wa.w;
  }
#pragma unroll
  for (int m = 1; m < 64; m <<= 1) acc += __shfl_xor(acc, m, 64);
  if (lane == 0) out[gw] = acc + bd[o];
}

// ---- 8-phase-style 256x256 GEMM, BK=32, 4-deep LDS ring, counted vmcnt ----
// 512 thr = 8 waves (2M x 4N), per-wave output 128x64. Per tile: 2 phases
// (quadrants mh=0/1), 16 MFMA each. Stage tile t+2 while computing tile t.
__global__ void __launch_bounds__(512, 2)
gemm8(const unsigned short* __restrict__ Aw,   // pre-swizzled tiled bf16 [256*32 tiles]
      const unsigned short* __restrict__ Bw,   // pre-swizzled tiled bf16 [4*32 tiles]
      const float* __restrict__ decf,          // [32,1024]
      const float* __restrict__ cov,           // [32,2048]
      const float* __restrict__ wcov,          // [1024]
      const float* __restrict__ v,             // [1024]
      float* __restrict__ scores) {            // [32,2048] partials
  __shared__ char lds[131072];  // 4 bufs x (A 16KB + B 16KB)

  const int bid = blockIdx.x;
  const int swz = (bid & 7) * 128 + (bid >> 3);  // bijective: 1024 % 8 == 0
  const int s_tile = swz >> 2;  // 0..255
  const int ot = swz & 3;       // 0..3

  const int tid = threadIdx.x, lane = tid & 63;
  const int wid = tid >> 6, wm = wid >> 2, wn = wid & 3;
  const int fr = lane & 15, hi = lane >> 4;

  const char* gA = reinterpret_cast<const char*>(Aw) + (size_t)s_tile * 32 * 16384 + tid * 16;
  const char* gB = reinterpret_cast<const char*>(Bw) + (size_t)ot * 32 * 16384 + tid * 16;

#define STAGE_A(t) do {                                                           \
    const char* _s = gA + (size_t)(t) * 16384;                                    \
    char* _d = lds + ((t) & 3) * 32768 + tid * 16;                                \
    __builtin_amdgcn_global_load_lds((GAS*)(_s),        (LAS*)(_d),        16, 0, 0); \
    __builtin_amdgcn_global_load_lds((GAS*)(_s + 8192), (LAS*)(_d + 8192), 16, 0, 0); \
  } while (0)
#define STAGE_B(t) do {                                                           \
    const char* _s = gB + (size_t)(t) * 16384;                                    \
    char* _d = lds + ((t) & 3) * 32768 + 16384 + tid * 16;                        \
    __builtin_amdgcn_global_load_lds((GAS*)(_s),        (LAS*)(_d),        16, 0, 0); \
    __builtin_amdgcn_global_load_lds((GAS*)(_s + 8192), (LAS*)(_d + 8192), 16, 0, 0); \
  } while (0)
#define NOSTAGE ((void)0)
#define VM4 asm volatile("s_waitcnt vmcnt(4)" ::: "memory")
#define VM0 asm volatile("s_waitcnt vmcnt(0)" ::: "memory")
#define NOWAIT ((void)0)

  // frag read offsets (buf-relative); XOR swizzle matches cvt layout
  const int xr = (fr & 3) << 4;
  const int aOff = wm * 8192 + fr * 64 + ((hi * 16) ^ xr);           // + fm*1024
  const int bOff = 16384 + wn * 4096 + fr * 64 + ((hi * 16) ^ xr);   // + fn*1024

  f32x4 acc[8][4];
#pragma unroll
  for (int i = 0; i < 8; ++i)
#pragma unroll
    for (int j = 0; j < 4; ++j) acc[i][j] = (f32x4){0.f, 0.f, 0.f, 0.f};

  s16x8 afrag[4], bfrag[4];

#define PH_A(t, STAGE) do {                                                       \
    const char* Lb = lds + ((t) & 3) * 32768;                                     \
    _Pragma("unroll") for (int fn = 0; fn < 4; ++fn)                              \
      bfrag[fn] = *reinterpret_cast<const s16x8*>(Lb + bOff + fn * 1024);         \
    _Pragma("unroll") for (int fm = 0; fm < 4; ++fm)                              \
      afrag[fm] = *reinterpret_cast<const s16x8*>(Lb + aOff + fm * 1024);         \
    STAGE;                                                                        \
    __builtin_amdgcn_s_barrier();                                                 \
    asm volatile("s_waitcnt lgkmcnt(0)" ::: "memory");                            \
    __builtin_amdgcn_sched_barrier(0);                                            \
    __builtin_amdgcn_s_setprio(1);                                                \
    _Pragma("unroll") for (int fm = 0; fm < 4; ++fm)                              \
      _Pragma("unroll") for (int fn = 0; fn < 4; ++fn)                            \
        acc[fm][fn] = __builtin_amdgcn_mfma_f32_16x16x32_bf16(                    \
            afrag[fm], bfrag[fn], acc[fm][fn], 0, 0, 0);                          \
    __builtin_amdgcn_s_setprio(0);                                                \
    __builtin_amdgcn_s_barrier();                                                 \
  } while (0)

#define PH_B(t, STAGE, WAIT) do {                                                 \
    const char* Lb = lds + ((t) & 3) * 32768;                                     \
    _Pragma("unroll") for (int fm = 0; fm < 4; ++fm)                              \
      afrag[fm] = *reinterpret_cast<const s16x8*>(Lb + aOff + (fm + 4) * 1024);   \
    STAGE;                                                                        \
    WAIT;                                                                         \
    __builtin_amdgcn_s_barrier();                                                 \
    asm volatile("s_waitcnt lgkmcnt(0)" ::: "memory");                            \
    __builtin_amdgcn_sched_barrier(0);                                            \
    __builtin_amdgcn_s_setprio(1);                                                \
    _Pragma("unroll") for (int fm = 0; fm < 4; ++fm)                              \
      _Pragma("unroll") for (int fn = 0; fn < 4; ++fn)                            \
        acc[fm + 4][fn] = __builtin_amdgcn_mfma_f32_16x16x32_bf16(                \
            afrag[fm], bfrag[fn], acc[fm + 4][fn], 0, 0, 0);                      \
    __builtin_amdgcn_s_setprio(0);                                                \
    __builtin_amdgcn_s_barrier();                                                 \
  } while (0)

  // prologue: stage tiles 0 and 1; wait tile 0 landed (own 4 oldest), sync all waves
  STAGE_A(0); STAGE_B(0);
  STAGE_A(1); STAGE_B(1);
  VM4;
  __builtin_amdgcn_s_barrier();

  // main: tiles 0..29, stage t+2, drain tile t+1's loads at end of tile (vmcnt(4))
  for (int t = 0; t < 30; ++t) {
    PH_A(t, STAGE_A(t + 2));
    PH_B(t, STAGE_B(t + 2), VM4);
  }
  // tail: tile 30 (drain tile 31 fully), tile 31
  PH_A(30, NOSTAGE);
  PH_B(30, NOSTAGE, VM0);
  PH_A(31, NOSTAGE);
  PH_B(31, NOSTAGE, NOWAIT);

#undef PH_A
#undef PH_B
#undef STAGE_A
#undef STAGE_B

  // epilogue: C/D layout col(fr)=o, row=(hi*4+reg)=s  [R1/R2-verified]
  const int row0 = s_tile * 256 + wm * 128 + hi * 4;
  const int o0 = ot * 256 + wn * 64 + fr;
  const int bb = s_tile >> 3;

  float vv[4], wv[4], dv[4];
#pragma unroll
  for (int fn = 0; fn < 4; ++fn) {
    int o = o0 + fn * 16;
    vv[fn] = v[o];
    wv[fn] = wcov[o];
    dv[fn] = decf[bb * 1024 + o];
  }

#pragma unroll
  for (int fm = 0; fm < 8; ++fm) {
#pragma unroll
    for (int r = 0; r < 4; ++r) {
      int s_flat = row0 + fm * 16 + r;
      float c = cov[s_flat];
      float sum = 0.f;
#pragma unroll
      for (int fn = 0; fn < 4; ++fn) {
        float x = acc[fm][fn][r] + dv[fn] + c * wv[fn];
        sum += tanhf(x) * vv[fn];
      }
      sum += __shfl_xor(sum, 1, 64);
      sum += __shfl_xor(sum, 2, 64);
      sum += __shfl_xor(sum, 4, 64);
      sum += __shfl_xor(sum, 8, 64);
      if (fr == 0) atomicAdd(&scores[s_flat], sum);
    }
  }
}

// ---- softmax over S=2048 per batch row ----
__global__ void softmax_kernel(const float* __restrict__ scores, float* __restrict__ out) {
  int b = blockIdx.x;
  int tid = threadIdx.x;
  int lane = tid & 63, w = tid >> 6;
  const float* row = scores + (size_t)b * Ss;
  float vals[8];
#pragma unroll
  for (int k = 0; k < 8; ++k) vals[k] = row[tid + k * 256];
  float m = vals[0];
#pragma unroll
  for (int k = 1; k < 8; ++k) m = fmaxf(m, vals[k]);
#pragma unroll
  for (int off = 1; off < 64; off <<= 1) m = fmaxf(m, __shfl_xor(m, off, 64));
  __shared__ float sm[4], ss[4];
  if (lane == 0) sm[w] = m;
  __syncthreads();
  m = fmaxf(fmaxf(sm[0], sm[1]), fmaxf(sm[2], sm[3]));
  float s = 0.f;
#pragma unroll
  for (int k = 0; k < 8; ++k) { vals[k] = __expf(vals[k] - m); s += vals[k]; }
#pragma unroll
  for (int off = 1; off < 64; off <<= 1) s += __shfl_xor(s, off, 64);
  if (lane == 0) ss[w] = s;
  __syncthreads();
  s = ss[0] + ss[1] + ss[2] + ss[3];
  float inv = 1.f / s;
#pragma unroll
  for (int k = 0; k < 8; ++k) out[(size_t)b * Ss + tid + k * 256] = vals[k] * inv;
}

extern "C" void kernel_launch(void* const* d_in, const int* in_sizes, int n_in,
                              void* d_out, int out_size, void* d_ws, size_t ws_size,
                              hipStream_t stream) {
  const float* dh    = (const float*)d_in[0];  // [32,1,1024]
  const float* enc   = (const float*)d_in[1];  // [32,2048,1024]
  const float* cov   = (const float*)d_in[2];  // [32,2048]
  const float* W_enc = (const float*)d_in[3];  // [1024,1024]
  const float* W_dec = (const float*)d_in[4];  // [1024,1024]
  const float* b_dec = (const float*)d_in[5];  // [1024]
  const float* w_cov = (const float*)d_in[6];  // [1024]
  const float* v     = (const float*)d_in[7];  // [1024]
  float* out = (float*)d_out;

  char* ws = (char*)d_ws;
  unsigned short* A_bf  = (unsigned short*)ws;                   // 128 MB tiled swizzled
  unsigned short* W_bf  = (unsigned short*)(ws + 134217728);     // 2 MB tiled swizzled
  float*          decf  = (float*)(ws + 136314880);              // 128 KB
  float*          score = (float*)(ws + 136445952);              // 256 KB

  hipMemsetAsync(score, 0, (size_t)Bb * Ss * sizeof(float), stream);
  cvt_swz_kernel<<<32768, 256, 0, stream>>>(enc, A_bf);    // 65536 rows
  cvt_swz_kernel<<<512, 256, 0, stream>>>(W_enc, W_bf);    // 1024 rows
  dec_feat_kernel<<<(Bb * Hh) / 4, 256, 0, stream>>>(dh, W_dec, b_dec, decf);
  gemm8<<<1024, 512, 0, stream>>>(A_bf, W_bf, decf, cov, w_cov, v, score);
  softmax_kernel<<<Bb, 256, 0, stream>>>(score, out);
}

// Round 7
// 250.281 us; speedup vs baseline: 1.2161x; 1.2161x over previous
//
#include <hip/hip_runtime.h>
#include <hip/hip_bf16.h>

#define Bb 32
#define Ss 2048
#define Hh 1024

typedef __attribute__((ext_vector_type(4))) float f32x4;
typedef __attribute__((ext_vector_type(8))) short s16x8;

#define GAS const __attribute__((address_space(1))) unsigned int
#define LAS __attribute__((address_space(3))) unsigned int

__device__ __forceinline__ unsigned short f2bf(float x) {
  unsigned int u = __float_as_uint(x);
  u = (u + 0x7fffu + ((u >> 16) & 1u)) >> 16;
  return (unsigned short)u;
}

__device__ __forceinline__ unsigned short f2bf_n(float x) {
  union { __hip_bfloat16 h; unsigned short u; } c;
  c.h = __float2bfloat16(x);
  return c.u;
}

// ---- W_enc fp32 -> bf16, tiled [ot(8)][kt(32)] 8KB tiles of 128 rows x 32 k,
// PRE-SWIZZLED: byte-in-tile = r*64 + ((2*k) ^ (((r>>1)&3)<<4)), r = o&127.
__global__ void cvt_w_kernel(const float* __restrict__ W, unsigned short* __restrict__ out) {
  int g = blockIdx.x * blockDim.x + threadIdx.x;  // 131072 threads, one 16B slot each
  int o = g >> 7;
  int kc8 = (g & 127) << 3;  // k start (8 floats)
  const float4* src = reinterpret_cast<const float4*>(W + (size_t)o * Hh + kc8);
  float4 a = src[0], b = src[1];
  union { unsigned short u[8]; uint4 q; } rr;
  rr.u[0] = f2bf(a.x); rr.u[1] = f2bf(a.y); rr.u[2] = f2bf(a.z); rr.u[3] = f2bf(a.w);
  rr.u[4] = f2bf(b.x); rr.u[5] = f2bf(b.y); rr.u[6] = f2bf(b.z); rr.u[7] = f2bf(b.w);
  int ot = o >> 7, r = o & 127, kt = kc8 >> 5, k0 = kc8 & 31;
  size_t byte = (size_t)(ot * 32 + kt) * 8192
              + (size_t)(r * 64 + ((2 * k0) ^ (((r >> 1) & 3) << 4)));
  *reinterpret_cast<uint4*>(reinterpret_cast<char*>(out) + byte) = rr.q;
}

// ---- dec_feature[b][o] = dot(dh[b], W_dec[o]) + b_dec[o], fp32, wave per (b,o) ----
__global__ void dec_feat_kernel(const float* __restrict__ dh,
                                const float* __restrict__ Wd,
                                const float* __restrict__ bd,
                                float* __restrict__ out) {
  int gw = blockIdx.x * 4 + (threadIdx.x >> 6);
  int lane = threadIdx.x & 63;
  int b = gw >> 10;
  int o = gw & 1023;
  const float4* x = reinterpret_cast<const float4*>(dh + (size_t)b * Hh);
  const float4* w = reinterpret_cast<const float4*>(Wd + (size_t)o * Hh);
  float acc = 0.f;
#pragma unroll
  for (int it = 0; it < 4; ++it) {
    float4 xa = x[lane + it * 64];
    float4 wa = w[lane + it * 64];
    acc += xa.x * wa.x + xa.y * wa.y + xa.z * wa.z + xa.w * wa.w;
  }
#pragma unroll
  for (int m = 1; m < 64; m <<= 1) acc += __shfl_xor(acc, m, 64);
  if (lane == 0) out[gw] = acc + bd[o];
}

// ---- fused GEMM: A staged fp32 (per-lane XOR-swizzled source, in-reg cvt),
// B bf16 from pre-swizzled Wswz. 128x128 tile, BK=32, 4 waves, R1 schedule.
// LDS/buf: A 16KB (rows 128B, slot^=(r&7)) + B 8KB (rows 64B, slot^=((r>>1)&3))
__global__ void __launch_bounds__(256, 2)
gemm_fused(const float* __restrict__ A,            // enc fp32 [65536][1024]
           const unsigned short* __restrict__ Bw,  // Wswz tiled/swizzled bf16
           const float* __restrict__ decf,         // [32,1024]
           const float* __restrict__ cov,          // [32,2048]
           const float* __restrict__ wcov,         // [1024]
           const float* __restrict__ v,            // [1024]
           float* __restrict__ scores) {           // [32,2048] partials
  __shared__ char lds[49152];  // 2 bufs x 24KB (A 16KB @0, B 8KB @16384)

  const int bid = blockIdx.x;
  const int swz = (bid & 7) * 512 + (bid >> 3);  // bijective: 4096 % 8 == 0
  const int s_tile = swz >> 3;  // 0..511
  const int o_tile = swz & 7;   // 0..7

  const int tid = threadIdx.x;
  const int lane = tid & 63;
  const int wid = tid >> 6;
  const int wr = wid >> 1, wc = wid & 1;   // 2x2 wave grid, 64x64 out each
  const int fr = lane & 15, hi = lane >> 4;

  // A staging: wave stages rows (wid*32 + i*8 + fr_l); lane's slot s8 holds k-group s8^fr_l
  const int fr_l = lane >> 3, s8 = lane & 7;
  const float* gA0 = A + (size_t)(s_tile * 128 + wid * 32 + fr_l) * 1024 + ((s8 ^ fr_l) << 2);
  // B staging: linear from pre-swizzled tiles, 256 thr x 16B x 2 rounds = 8KB exact
  const char* gB0 = reinterpret_cast<const char*>(Bw) + (size_t)o_tile * 262144 + tid * 16;

#define STAGE(b, kt) do {                                                          \
    char* _dA = lds + (b) * 24576 + wid * 4096 + lane * 16;                        \
    const float* _sA = gA0 + (size_t)(kt) * 32;                                    \
    _Pragma("unroll") for (int i = 0; i < 4; ++i)                                  \
      __builtin_amdgcn_global_load_lds((GAS*)(_sA + (size_t)i * 8192),             \
                                       (LAS*)(_dA + i * 1024), 16, 0, 0);          \
    char* _dB = lds + (b) * 24576 + 16384 + tid * 16;                              \
    const char* _sB = gB0 + (size_t)(kt) * 8192;                                   \
    _Pragma("unroll") for (int i = 0; i < 2; ++i)                                  \
      __builtin_amdgcn_global_load_lds((GAS*)(_sB + i * 4096),                     \
                                       (LAS*)(_dB + i * 4096), 16, 0, 0);          \
  } while (0)

  // frag read offsets
  const int xrA = (fr & 7) << 4;
  const int xrB = ((fr >> 1) & 3) << 4;
  const int aBase = (wr * 64 + fr) * 128;          // + fm*2048 + ((hi*32 [+16]) ^ xrA)
  const int bBase = 16384 + (wc * 64 + fr) * 64;   // + fn*1024 + ((hi*16) ^ xrB)

  f32x4 acc[4][4];
#pragma unroll
  for (int i = 0; i < 4; ++i)
#pragma unroll
    for (int j = 0; j < 4; ++j) acc[i][j] = (f32x4){0.f, 0.f, 0.f, 0.f};

  STAGE(0, 0);
  __syncthreads();
  int buf = 0;

  for (int kt = 0; kt < 32; ++kt) {
    if (kt < 31) STAGE(buf ^ 1, kt + 1);
    const char* Lb = lds + buf * 24576;
    s16x8 bfrag[4];
#pragma unroll
    for (int fn = 0; fn < 4; ++fn)
      bfrag[fn] = *reinterpret_cast<const s16x8*>(Lb + bBase + fn * 1024 + ((hi * 16) ^ xrB));
#pragma unroll
    for (int fm = 0; fm < 4; ++fm) {
      f32x4 a0 = *reinterpret_cast<const f32x4*>(Lb + aBase + fm * 2048 + ((hi * 32) ^ xrA));
      f32x4 a1 = *reinterpret_cast<const f32x4*>(Lb + aBase + fm * 2048 + ((hi * 32 + 16) ^ xrA));
      union { unsigned short u[8]; s16x8 v; } af;
      af.u[0] = f2bf_n(a0[0]); af.u[1] = f2bf_n(a0[1]);
      af.u[2] = f2bf_n(a0[2]); af.u[3] = f2bf_n(a0[3]);
      af.u[4] = f2bf_n(a1[0]); af.u[5] = f2bf_n(a1[1]);
      af.u[6] = f2bf_n(a1[2]); af.u[7] = f2bf_n(a1[3]);
#pragma unroll
      for (int fn = 0; fn < 4; ++fn)
        acc[fm][fn] = __builtin_amdgcn_mfma_f32_16x16x32_bf16(af.v, bfrag[fn], acc[fm][fn], 0, 0, 0);
    }
    __syncthreads();
    buf ^= 1;
  }
#undef STAGE

  // epilogue: C/D layout col(fr)=o, row=(hi*4+reg)=s  [R1-verified]
  const int row0 = s_tile * 128 + wr * 64 + hi * 4;
  const int o0 = o_tile * 128 + wc * 64 + fr;
  const int bb = s_tile >> 4;

  float vv[4], wv[4], dv[4];
#pragma unroll
  for (int fn = 0; fn < 4; ++fn) {
    int o = o0 + fn * 16;
    vv[fn] = v[o];
    wv[fn] = wcov[o];
    dv[fn] = decf[bb * 1024 + o];
  }

#pragma unroll
  for (int fm = 0; fm < 4; ++fm) {
#pragma unroll
    for (int r = 0; r < 4; ++r) {
      int s_flat = row0 + fm * 16 + r;
      float c = cov[s_flat];
      float sum = 0.f;
#pragma unroll
      for (int fn = 0; fn < 4; ++fn) {
        float x = acc[fm][fn][r] + dv[fn] + c * wv[fn];
        // fast tanh: 1 - 2/(e^{2x}+1), clamped (exact to fp32 for |x|>9)
        float xc = fminf(fmaxf(x, -15.f), 15.f);
        float e2 = __expf(2.f * xc);
        sum += (1.f - 2.f / (e2 + 1.f)) * vv[fn];
      }
      sum += __shfl_xor(sum, 1, 64);
      sum += __shfl_xor(sum, 2, 64);
      sum += __shfl_xor(sum, 4, 64);
      sum += __shfl_xor(sum, 8, 64);
      if (fr == 0) atomicAdd(&scores[s_flat], sum);
    }
  }
}

// ---- softmax over S=2048 per batch row ----
__global__ void softmax_kernel(const float* __restrict__ scores, float* __restrict__ out) {
  int b = blockIdx.x;
  int tid = threadIdx.x;
  int lane = tid & 63, w = tid >> 6;
  const float* row = scores + (size_t)b * Ss;
  float vals[8];
#pragma unroll
  for (int k = 0; k < 8; ++k) vals[k] = row[tid + k * 256];
  float m = vals[0];
#pragma unroll
  for (int k = 1; k < 8; ++k) m = fmaxf(m, vals[k]);
#pragma unroll
  for (int off = 1; off < 64; off <<= 1) m = fmaxf(m, __shfl_xor(m, off, 64));
  __shared__ float sm[4], ss[4];
  if (lane == 0) sm[w] = m;
  __syncthreads();
  m = fmaxf(fmaxf(sm[0], sm[1]), fmaxf(sm[2], sm[3]));
  float s = 0.f;
#pragma unroll
  for (int k = 0; k < 8; ++k) { vals[k] = __expf(vals[k] - m); s += vals[k]; }
#pragma unroll
  for (int off = 1; off < 64; off <<= 1) s += __shfl_xor(s, off, 64);
  if (lane == 0) ss[w] = s;
  __syncthreads();
  s = ss[0] + ss[1] + ss[2] + ss[3];
  float inv = 1.f / s;
#pragma unroll
  for (int k = 0; k < 8; ++k) out[(size_t)b * Ss + tid + k * 256] = vals[k] * inv;
}

extern "C" void kernel_launch(void* const* d_in, const int* in_sizes, int n_in,
                              void* d_out, int out_size, void* d_ws, size_t ws_size,
                              hipStream_t stream) {
  const float* dh    = (const float*)d_in[0];  // [32,1,1024]
  const float* enc   = (const float*)d_in[1];  // [32,2048,1024]
  const float* cov   = (const float*)d_in[2];  // [32,2048]
  const float* W_enc = (const float*)d_in[3];  // [1024,1024]
  const float* W_dec = (const float*)d_in[4];  // [1024,1024]
  const float* b_dec = (const float*)d_in[5];  // [1024]
  const float* w_cov = (const float*)d_in[6];  // [1024]
  const float* v     = (const float*)d_in[7];  // [1024]
  float* out = (float*)d_out;

  char* ws = (char*)d_ws;
  unsigned short* Wswz = (unsigned short*)ws;               // 2 MB tiled+swizzled bf16
  float*          decf = (float*)(ws + 2097152);            // 128 KB
  float*          score = (float*)(ws + 2097152 + 131072);  // 256 KB

  hipMemsetAsync(score, 0, (size_t)Bb * Ss * sizeof(float), stream);
  cvt_w_kernel<<<512, 256, 0, stream>>>(W_enc, Wswz);
  dec_feat_kernel<<<(Bb * Hh) / 4, 256, 0, stream>>>(dh, W_dec, b_dec, decf);
  gemm_fused<<<4096, 256, 0, stream>>>(enc, Wswz, decf, cov, w_cov, v, score);
  softmax_kernel<<<Bb, 256, 0, stream>>>(score, out);
}